// Round 10
// baseline (246.582 us; speedup 1.0000x reference)
//
#include <hip/hip_runtime.h>

typedef unsigned int uint32;
typedef unsigned short ush;
typedef __attribute__((ext_vector_type(8))) short short8;   // bf16x8 MFMA frag
typedef __attribute__((ext_vector_type(4))) float f32x4;    // fp32x4 acc frag

__device__ __forceinline__ ush f2bf(float f) {
    union { float f; uint32 u; } v; v.f = f;
    uint32 r = v.u + 0x7fffu + ((v.u >> 16) & 1u);   // RNE
    return (ush)(r >> 16);
}
__device__ __forceinline__ float bfl(uint32 u) {             // low ushort -> f32
    union { uint32 u; float f; } v; v.u = u << 16; return v.f;
}
__device__ __forceinline__ float bfh(uint32 u) {             // high ushort -> f32
    union { uint32 u; float f; } v; v.u = u & 0xffff0000u; return v.f;
}

#define BSH 6       // bucket = dst >> 6 (64 nodes/bucket)
#define NBMAX 1024  // max buckets (N=50000 -> 782)
#define CHUNK 2048  // edges per block in binning kernels

// ---------------- binned CSR build (contention-free) ----------------
// rec packing: src in bits[15:0] (N<=65536), dst&63 in bits[21:16].

__global__ void k_zerob(int* __restrict__ b, int nb) {
    int i = blockIdx.x * 256 + threadIdx.x;
    if (i < nb) b[i] = 0;
}

__global__ __launch_bounds__(256) void k_bcount(const int* __restrict__ dst,
                                                int* __restrict__ bcnt, int e, int nb) {
    __shared__ int cnt[NBMAX];
    for (int i = threadIdx.x; i < nb; i += 256) cnt[i] = 0;
    __syncthreads();
    int base = blockIdx.x * CHUNK;
    int end = min(e, base + CHUNK);
    for (int i = base + threadIdx.x; i < end; i += 256)
        atomicAdd(&cnt[dst[i] >> BSH], 1);
    __syncthreads();
    for (int i = threadIdx.x; i < nb; i += 256) {
        int c = cnt[i];
        if (c) atomicAdd(&bcnt[i], c);
    }
}

__global__ void k_bscan(const int* __restrict__ bcnt, int* __restrict__ bstart,
                        int* __restrict__ bcur, int nb, int e) {
    __shared__ int s[256];
    __shared__ int carry;
    int tid = threadIdx.x;
    if (tid == 0) carry = 0;
    __syncthreads();
    for (int base = 0; base < nb; base += 256) {
        int v = (base + tid < nb) ? bcnt[base + tid] : 0;
        s[tid] = v;
        __syncthreads();
        for (int off = 1; off < 256; off <<= 1) {
            int t = (tid >= off) ? s[tid - off] : 0;
            __syncthreads();
            s[tid] += t;
            __syncthreads();
        }
        int ex = s[tid] - v + carry;
        if (base + tid < nb) { bstart[base + tid] = ex; bcur[base + tid] = ex; }
        __syncthreads();
        if (tid == 0) carry += s[255];
        __syncthreads();
    }
    if (tid == 0) bstart[nb] = e;
}

__global__ __launch_bounds__(256) void k_binA2(const int* __restrict__ src,
                                               const int* __restrict__ dst,
                                               int* __restrict__ bcur,
                                               int* __restrict__ rec, int e, int nb) {
    __shared__ int cnt[NBMAX];
    __shared__ int bas[NBMAX];
    __shared__ int off[NBMAX];
    for (int i = threadIdx.x; i < nb; i += 256) { cnt[i] = 0; off[i] = 0; }
    __syncthreads();
    int base = blockIdx.x * CHUNK;
    int end = min(e, base + CHUNK);
    for (int i = base + threadIdx.x; i < end; i += 256)
        atomicAdd(&cnt[dst[i] >> BSH], 1);
    __syncthreads();
    for (int i = threadIdx.x; i < nb; i += 256) {
        int c = cnt[i];
        if (c) bas[i] = atomicAdd(&bcur[i], c);
    }
    __syncthreads();
    for (int i = base + threadIdx.x; i < end; i += 256) {
        int s = src[i];
        int d = dst[i];
        int b = d >> BSH;
        int p = bas[b] + atomicAdd(&off[b], 1);
        rec[p] = (s & 0xFFFF) | ((d & 63) << 16);
    }
}

__global__ __launch_bounds__(256) void k_degB(const int* __restrict__ rec,
                                              const int* __restrict__ bstart,
                                              int* __restrict__ rowstart,
                                              float* __restrict__ inv, int n, int e) {
    __shared__ int cnt[64];
    int b = blockIdx.x;
    int st = bstart[b], en = bstart[b + 1];
    if (threadIdx.x < 64) cnt[threadIdx.x] = 0;
    __syncthreads();
    for (int i = st + threadIdx.x; i < en; i += 256)
        atomicAdd(&cnt[(rec[i] >> 16) & 63], 1);
    __syncthreads();
    if (threadIdx.x < 64) {
        int c = cnt[threadIdx.x];
        int incl = c;
        #pragma unroll
        for (int o2 = 1; o2 < 64; o2 <<= 1) {
            int t = __shfl_up(incl, o2, 64);
            if ((int)threadIdx.x >= o2) incl += t;
        }
        int node = (b << BSH) + threadIdx.x;
        if (node < n) {
            rowstart[node] = st + incl - c;
            inv[node] = rsqrtf((float)c + 1.0f);
        }
    }
    if (b == 0 && threadIdx.x == 0) rowstart[n] = e;
}

__global__ __launch_bounds__(256) void k_fillB2(const int* __restrict__ rec,
                                                const int* __restrict__ bstart,
                                                const int* __restrict__ rowstart,
                                                const float* __restrict__ inv,
                                                int2* __restrict__ es, int n) {
    __shared__ int cur[64];
    int b = blockIdx.x;
    int st = bstart[b], en = bstart[b + 1];
    if (threadIdx.x < 64) {
        int node = (b << BSH) + threadIdx.x;
        cur[threadIdx.x] = (node < n) ? (rowstart[node] - st) : 0;
    }
    __syncthreads();
    for (int i = st + threadIdx.x; i < en; i += 256) {
        int r = rec[i];
        int s = r & 0xFFFF;
        int slot = atomicAdd(&cur[(r >> 16) & 63], 1);
        es[st + slot] = make_int2(s, __float_as_int(inv[s]));
    }
}

// ---------------- MFMA GEMM layer 1: fp32 x, bf16x3 split ----------------
// h[n,128](bf16) = x[n,128] @ W1. Block 128 rows, 4 waves 2x2, K=128 one-shot.
// W staged fp32->bf16 hi/lo in-kernel (transposed [col][K], XOR-swizzled).
__global__ __launch_bounds__(256) void k_gemm1m(const float* __restrict__ x,
                                                const float* __restrict__ W,
                                                ush* __restrict__ h, int n) {
    constexpr int COUT = 128, CT = 4;
    __shared__ short xh[128 * 128];        // 32 KiB
    __shared__ short xl[128 * 128];        // 32 KiB
    __shared__ short wh[COUT * 128];       // 32 KiB
    __shared__ short wl[COUT * 128];       // 32 KiB
    int tid = threadIdx.x;
    int row0 = blockIdx.x * 128;

    for (int i = tid; i < 128 * COUT; i += 256) {
        int k = i >> 7, col = i & 127;
        float w = W[i];
        ush hb = f2bf(w);
        int byte = ((col * 128 + k) * 2) ^ ((col & 7) << 4);
        *(ush*)((char*)wh + byte) = hb;
        *(ush*)((char*)wl + byte) = f2bf(w - bfl((uint32)hb));
    }
    #pragma unroll
    for (int i = 0; i < 8; ++i) {
        int rl = (tid >> 4) + i * 16;
        int k0 = (tid & 15) * 8;
        int row = row0 + rl;
        float f[8];
        if (row < n) {
            float4 p0 = *(const float4*)&x[(size_t)row * 128 + k0];
            float4 p1 = *(const float4*)&x[(size_t)row * 128 + k0 + 4];
            f[0] = p0.x; f[1] = p0.y; f[2] = p0.z; f[3] = p0.w;
            f[4] = p1.x; f[5] = p1.y; f[6] = p1.z; f[7] = p1.w;
        } else {
            #pragma unroll
            for (int j = 0; j < 8; ++j) f[j] = 0.f;
        }
        short8 hi, lo;
        #pragma unroll
        for (int j = 0; j < 8; ++j) {
            ush hb = f2bf(f[j]);
            hi[j] = (short)hb;
            lo[j] = (short)f2bf(f[j] - bfl((uint32)hb));
        }
        int byte = (rl * 256 + k0 * 2) ^ ((rl & 7) << 4);
        *(short8*)((char*)xh + byte) = hi;
        *(short8*)((char*)xl + byte) = lo;
    }
    __syncthreads();

    int wid = tid >> 6, lane = tid & 63;
    int arow = (wid >> 1) * 64;
    int bcol = (wid & 1) * (COUT / 2);
    int l15 = lane & 15, kg = lane >> 4;

    f32x4 acc[4][CT];
    #pragma unroll
    for (int rt = 0; rt < 4; ++rt)
        #pragma unroll
        for (int ct = 0; ct < CT; ++ct)
            acc[rt][ct] = (f32x4){0.f, 0.f, 0.f, 0.f};

    #pragma unroll
    for (int ks = 0; ks < 4; ++ks) {
        short8 ah[4], al[4];
        #pragma unroll
        for (int rt = 0; rt < 4; ++rt) {
            int r = arow + rt * 16 + l15;
            int byte = (r * 256 + ks * 64 + kg * 16) ^ ((r & 7) << 4);
            ah[rt] = *(const short8*)((const char*)xh + byte);
            al[rt] = *(const short8*)((const char*)xl + byte);
        }
        #pragma unroll
        for (int ct = 0; ct < CT; ++ct) {
            int c = bcol + ct * 16 + l15;
            int byte = (c * 256 + ks * 64 + kg * 16) ^ ((c & 7) << 4);
            short8 bh = *(const short8*)((const char*)wh + byte);
            short8 bl = *(const short8*)((const char*)wl + byte);
            #pragma unroll
            for (int rt = 0; rt < 4; ++rt) {
                acc[rt][ct] = __builtin_amdgcn_mfma_f32_16x16x32_bf16(ah[rt], bh, acc[rt][ct], 0, 0, 0);
                acc[rt][ct] = __builtin_amdgcn_mfma_f32_16x16x32_bf16(al[rt], bh, acc[rt][ct], 0, 0, 0);
                acc[rt][ct] = __builtin_amdgcn_mfma_f32_16x16x32_bf16(ah[rt], bl, acc[rt][ct], 0, 0, 0);
            }
        }
    }

    int rq = kg * 4;
    #pragma unroll
    for (int rt = 0; rt < 4; ++rt)
        #pragma unroll
        for (int ct = 0; ct < CT; ++ct) {
            int col = bcol + ct * 16 + l15;
            #pragma unroll
            for (int q = 0; q < 4; ++q) {
                int row = row0 + arow + rt * 16 + rq + q;
                if (row < n) h[(size_t)row * COUT + col] = f2bf(acc[rt][ct][q]);
            }
        }
}

// ---------------- MFMA GEMM layer 2: bf16 act input, bf16x2 split ----------
// h[n,64](bf16) = a[n,128](bf16) @ W2.  LDS 64KB -> 2 blocks/CU.
__global__ __launch_bounds__(256) void k_gemm2m(const ush* __restrict__ a,
                                                const float* __restrict__ W,
                                                ush* __restrict__ h, int n) {
    constexpr int COUT = 64, CT = 2;
    __shared__ short xh[128 * 128];        // 32 KiB
    __shared__ short wh[COUT * 128];       // 16 KiB
    __shared__ short wl[COUT * 128];       // 16 KiB
    int tid = threadIdx.x;
    int row0 = blockIdx.x * 128;

    for (int i = tid; i < 128 * COUT; i += 256) {
        int k = i >> 6, col = i & 63;
        float w = W[i];
        ush hb = f2bf(w);
        int byte = ((col * 128 + k) * 2) ^ ((col & 7) << 4);
        *(ush*)((char*)wh + byte) = hb;
        *(ush*)((char*)wl + byte) = f2bf(w - bfl((uint32)hb));
    }
    #pragma unroll
    for (int i = 0; i < 8; ++i) {
        int rl = (tid >> 4) + i * 16;
        int k0 = (tid & 15) * 8;
        int row = row0 + rl;
        short8 v;
        #pragma unroll
        for (int j = 0; j < 8; ++j) v[j] = 0;
        if (row < n) v = *(const short8*)&a[(size_t)row * 128 + k0];
        int byte = (rl * 256 + k0 * 2) ^ ((rl & 7) << 4);
        *(short8*)((char*)xh + byte) = v;
    }
    __syncthreads();

    int wid = tid >> 6, lane = tid & 63;
    int arow = (wid >> 1) * 64;
    int bcol = (wid & 1) * (COUT / 2);
    int l15 = lane & 15, kg = lane >> 4;

    f32x4 acc[4][CT];
    #pragma unroll
    for (int rt = 0; rt < 4; ++rt)
        #pragma unroll
        for (int ct = 0; ct < CT; ++ct)
            acc[rt][ct] = (f32x4){0.f, 0.f, 0.f, 0.f};

    #pragma unroll
    for (int ks = 0; ks < 4; ++ks) {
        short8 ah[4];
        #pragma unroll
        for (int rt = 0; rt < 4; ++rt) {
            int r = arow + rt * 16 + l15;
            int byte = (r * 256 + ks * 64 + kg * 16) ^ ((r & 7) << 4);
            ah[rt] = *(const short8*)((const char*)xh + byte);
        }
        #pragma unroll
        for (int ct = 0; ct < CT; ++ct) {
            int c = bcol + ct * 16 + l15;
            int byte = (c * 256 + ks * 64 + kg * 16) ^ ((c & 7) << 4);
            short8 bh = *(const short8*)((const char*)wh + byte);
            short8 bl = *(const short8*)((const char*)wl + byte);
            #pragma unroll
            for (int rt = 0; rt < 4; ++rt) {
                acc[rt][ct] = __builtin_amdgcn_mfma_f32_16x16x32_bf16(ah[rt], bh, acc[rt][ct], 0, 0, 0);
                acc[rt][ct] = __builtin_amdgcn_mfma_f32_16x16x32_bf16(ah[rt], bl, acc[rt][ct], 0, 0, 0);
            }
        }
    }

    int rq = kg * 4;
    #pragma unroll
    for (int rt = 0; rt < 4; ++rt)
        #pragma unroll
        for (int ct = 0; ct < CT; ++ct) {
            int col = bcol + ct * 16 + l15;
            #pragma unroll
            for (int q = 0; q < 4; ++q) {
                int row = row0 + arow + rt * 16 + rq + q;
                if (row < n) h[(size_t)row * COUT + col] = f2bf(acc[rt][ct][q]);
            }
        }
}

// ---------------- Gather (aggregation), bf16 source rows ----------------
// es[i] = {src, bits(inv_sqrt[src])}. One wave per destination node.
// OUTBF: write bf16 (layer-1 act); else fp32 (final out).
template <int COLS, bool RELU, bool OUTBF>
__global__ __launch_bounds__(256) void k_gather(const ush* __restrict__ h,
                                                const int* __restrict__ rowstart,
                                                const int2* __restrict__ es,
                                                const float* __restrict__ inv,
                                                const float* __restrict__ bias,
                                                void* __restrict__ outp, int n) {
    int wave = threadIdx.x >> 6;
    int lane = threadIdx.x & 63;
    int node = blockIdx.x * 4 + wave;
    if (node >= n) return;
    int s0 = rowstart[node];
    int s1 = rowstart[node + 1];
    float iv = inv[node];

    if constexpr (COLS == 128) {
        int c = lane * 2;
        float accx = 0.f, accy = 0.f;
        int i = s0;
        for (; i + 8 <= s1; i += 8) {
            int    a[8];
            float  w[8];
            uint32 u[8];
            #pragma unroll
            for (int j = 0; j < 8; ++j) {
                int2 r = es[i + j];
                a[j] = r.x;
                w[j] = __int_as_float(r.y);
            }
            #pragma unroll
            for (int j = 0; j < 8; ++j)
                u[j] = *(const uint32*)&h[(size_t)a[j] * 128 + c];
            #pragma unroll
            for (int j = 0; j < 8; ++j) {
                accx += w[j] * bfl(u[j]);
                accy += w[j] * bfh(u[j]);
            }
        }
        for (; i < s1; ++i) {
            int2 r = es[i];
            uint32 u = *(const uint32*)&h[(size_t)r.x * 128 + c];
            float w = __int_as_float(r.y);
            accx += w * bfl(u);
            accy += w * bfh(u);
        }
        uint32 us = *(const uint32*)&h[(size_t)node * 128 + c];
        float2 bb = *(const float2*)&bias[c];
        float ox = iv * accx + iv * iv * bfl(us) + bb.x;
        float oy = iv * accy + iv * iv * bfh(us) + bb.y;
        if (RELU) { ox = fmaxf(ox, 0.f); oy = fmaxf(oy, 0.f); }
        if constexpr (OUTBF) {
            uint32 pk = (uint32)f2bf(ox) | ((uint32)f2bf(oy) << 16);
            *(uint32*)&((ush*)outp)[(size_t)node * 128 + c] = pk;
        } else {
            *(float2*)&((float*)outp)[(size_t)node * 128 + c] = make_float2(ox, oy);
        }
    } else {
        int c = lane;
        float acc = 0.f;
        int i = s0;
        for (; i + 8 <= s1; i += 8) {
            int   a[8];
            float w[8];
            ush   u[8];
            #pragma unroll
            for (int j = 0; j < 8; ++j) {
                int2 r = es[i + j];
                a[j] = r.x;
                w[j] = __int_as_float(r.y);
            }
            #pragma unroll
            for (int j = 0; j < 8; ++j)
                u[j] = h[(size_t)a[j] * 64 + c];
            #pragma unroll
            for (int j = 0; j < 8; ++j)
                acc += w[j] * bfl((uint32)u[j]);
        }
        for (; i < s1; ++i) {
            int2 r = es[i];
            acc += __int_as_float(r.y) * bfl((uint32)h[(size_t)r.x * 64 + c]);
        }
        float self = bfl((uint32)h[(size_t)node * 64 + c]);
        float o = iv * acc + iv * iv * self + bias[c];
        if (RELU) o = fmaxf(o, 0.f);
        ((float*)outp)[(size_t)node * 64 + c] = o;
    }
}

// ---------------- launcher ----------------

extern "C" void kernel_launch(void* const* d_in, const int* in_sizes, int n_in,
                              void* d_out, int out_size, void* d_ws, size_t ws_size,
                              hipStream_t stream) {
    const float* x  = (const float*)d_in[0];
    const int*   ei = (const int*)d_in[1];
    const float* W1 = (const float*)d_in[2];
    const float* b1 = (const float*)d_in[3];
    const float* W2 = (const float*)d_in[4];
    const float* b2 = (const float*)d_in[5];
    float* out = (float*)d_out;

    const int N = in_sizes[0] / 128;   // 50000
    const int E = in_sizes[1] / 2;     // 800000
    const int NB = (N + 63) >> BSH;    // 782 buckets
    const int* src = ei;
    const int* dstp = ei + E;

    char* p = (char*)d_ws;
    auto take = [&](size_t bytes) {
        char* r = p;
        p += (bytes + 255) & ~(size_t)255;
        return r;
    };
    float* inv      = (float*)take((size_t)N * 4);
    int*   rowstart = (int*)take((size_t)(N + 1) * 4);
    int*   bcnt     = (int*)take((size_t)NB * 4);
    int*   bstart   = (int*)take((size_t)(NB + 1) * 4);
    int*   bcur     = (int*)take((size_t)NB * 4);
    int*   rec      = (int*)take((size_t)E * 4);         // packed src|dlocal
    int2*  es       = (int2*)take((size_t)E * 8);
    ush*   h1       = (ush*)take((size_t)N * 128 * 2);   // bf16
    ush*   act1     = (ush*)take((size_t)N * 128 * 2);   // bf16
    ush*   h2       = h1;   // h1 dead after gather-1

    const int nbC = (E + CHUNK - 1) / CHUNK;   // 391

    k_zerob <<<(NB + 255) / 256, 256, 0, stream>>>(bcnt, NB);
    k_bcount<<<nbC, 256, 0, stream>>>(dstp, bcnt, E, NB);
    k_bscan <<<1, 256, 0, stream>>>(bcnt, bstart, bcur, NB, E);
    k_binA2 <<<nbC, 256, 0, stream>>>(src, dstp, bcur, rec, E, NB);
    k_degB  <<<NB, 256, 0, stream>>>(rec, bstart, rowstart, inv, N, E);
    k_fillB2<<<NB, 256, 0, stream>>>(rec, bstart, rowstart, inv, es, N);

    const int gb = (N + 127) / 128;   // 391
    k_gemm1m<<<gb, 256, 0, stream>>>(x, W1, h1, N);
    k_gather<128, true, true><<<(N + 3) / 4, 256, 0, stream>>>(h1, rowstart, es, inv, b1, act1, N);
    k_gemm2m<<<gb, 256, 0, stream>>>(act1, W2, h2, N);
    k_gather<64, false, false><<<(N + 3) / 4, 256, 0, stream>>>(h2, rowstart, es, inv, b2, out, N);
}

// Round 11
// 234.852 us; speedup vs baseline: 1.0499x; 1.0499x over previous
//
#include <hip/hip_runtime.h>

typedef unsigned int uint32;
typedef unsigned short ush;
typedef __attribute__((ext_vector_type(8))) short short8;   // bf16x8 MFMA frag
typedef __attribute__((ext_vector_type(4))) float f32x4;    // fp32x4 acc frag

__device__ __forceinline__ ush f2bf(float f) {
    union { float f; uint32 u; } v; v.f = f;
    uint32 r = v.u + 0x7fffu + ((v.u >> 16) & 1u);   // RNE
    return (ush)(r >> 16);
}
__device__ __forceinline__ float bfl(uint32 u) {             // low ushort -> f32
    union { uint32 u; float f; } v; v.u = u << 16; return v.f;
}
__device__ __forceinline__ float bfh(uint32 u) {             // high ushort -> f32
    union { uint32 u; float f; } v; v.u = u & 0xffff0000u; return v.f;
}

#define BSH 6       // bucket = dst >> 6 (64 nodes/bucket)
#define NBMAX 1024  // max buckets (N=50000 -> 782)
#define CHUNK 4096  // edges per block in binning kernels (round-8 proven)

// ---------------- binned CSR build (contention-free) ----------------
// rec packing: src in bits[15:0] (N<=65536), dst&63 in bits[21:16].

__global__ void k_zerob(int* __restrict__ b, int nb) {
    int i = blockIdx.x * 256 + threadIdx.x;
    if (i < nb) b[i] = 0;
}

__global__ __launch_bounds__(256) void k_bcount(const int* __restrict__ dst,
                                                int* __restrict__ bcnt, int e, int nb) {
    __shared__ int cnt[NBMAX];
    for (int i = threadIdx.x; i < nb; i += 256) cnt[i] = 0;
    __syncthreads();
    int base = blockIdx.x * CHUNK;
    int end = min(e, base + CHUNK);
    for (int i = base + threadIdx.x; i < end; i += 256)
        atomicAdd(&cnt[dst[i] >> BSH], 1);
    __syncthreads();
    for (int i = threadIdx.x; i < nb; i += 256) {
        int c = cnt[i];
        if (c) atomicAdd(&bcnt[i], c);
    }
}

__global__ void k_bscan(const int* __restrict__ bcnt, int* __restrict__ bstart,
                        int* __restrict__ bcur, int nb, int e) {
    __shared__ int s[256];
    __shared__ int carry;
    int tid = threadIdx.x;
    if (tid == 0) carry = 0;
    __syncthreads();
    for (int base = 0; base < nb; base += 256) {
        int v = (base + tid < nb) ? bcnt[base + tid] : 0;
        s[tid] = v;
        __syncthreads();
        for (int off = 1; off < 256; off <<= 1) {
            int t = (tid >= off) ? s[tid - off] : 0;
            __syncthreads();
            s[tid] += t;
            __syncthreads();
        }
        int ex = s[tid] - v + carry;
        if (base + tid < nb) { bstart[base + tid] = ex; bcur[base + tid] = ex; }
        __syncthreads();
        if (tid == 0) carry += s[255];
        __syncthreads();
    }
    if (tid == 0) bstart[nb] = e;
}

__global__ __launch_bounds__(256) void k_binA2(const int* __restrict__ src,
                                               const int* __restrict__ dst,
                                               int* __restrict__ bcur,
                                               int* __restrict__ rec, int e, int nb) {
    __shared__ int cnt[NBMAX];
    __shared__ int bas[NBMAX];
    __shared__ int off[NBMAX];
    for (int i = threadIdx.x; i < nb; i += 256) { cnt[i] = 0; off[i] = 0; }
    __syncthreads();
    int base = blockIdx.x * CHUNK;
    int end = min(e, base + CHUNK);
    for (int i = base + threadIdx.x; i < end; i += 256)
        atomicAdd(&cnt[dst[i] >> BSH], 1);
    __syncthreads();
    for (int i = threadIdx.x; i < nb; i += 256) {
        int c = cnt[i];
        if (c) bas[i] = atomicAdd(&bcur[i], c);
    }
    __syncthreads();
    for (int i = base + threadIdx.x; i < end; i += 256) {
        int s = src[i];
        int d = dst[i];
        int b = d >> BSH;
        int p = bas[b] + atomicAdd(&off[b], 1);
        rec[p] = (s & 0xFFFF) | ((d & 63) << 16);
    }
}

__global__ __launch_bounds__(256) void k_degB(const int* __restrict__ rec,
                                              const int* __restrict__ bstart,
                                              int* __restrict__ rowstart,
                                              float* __restrict__ inv, int n, int e) {
    __shared__ int cnt[64];
    int b = blockIdx.x;
    int st = bstart[b], en = bstart[b + 1];
    if (threadIdx.x < 64) cnt[threadIdx.x] = 0;
    __syncthreads();
    for (int i = st + threadIdx.x; i < en; i += 256)
        atomicAdd(&cnt[(rec[i] >> 16) & 63], 1);
    __syncthreads();
    if (threadIdx.x < 64) {
        int c = cnt[threadIdx.x];
        int incl = c;
        #pragma unroll
        for (int o2 = 1; o2 < 64; o2 <<= 1) {
            int t = __shfl_up(incl, o2, 64);
            if ((int)threadIdx.x >= o2) incl += t;
        }
        int node = (b << BSH) + threadIdx.x;
        if (node < n) {
            rowstart[node] = st + incl - c;
            inv[node] = rsqrtf((float)c + 1.0f);
        }
    }
    if (b == 0 && threadIdx.x == 0) rowstart[n] = e;
}

__global__ __launch_bounds__(256) void k_fillB2(const int* __restrict__ rec,
                                                const int* __restrict__ bstart,
                                                const int* __restrict__ rowstart,
                                                const float* __restrict__ inv,
                                                int2* __restrict__ es, int n) {
    __shared__ int cur[64];
    int b = blockIdx.x;
    int st = bstart[b], en = bstart[b + 1];
    if (threadIdx.x < 64) {
        int node = (b << BSH) + threadIdx.x;
        cur[threadIdx.x] = (node < n) ? (rowstart[node] - st) : 0;
    }
    __syncthreads();
    for (int i = st + threadIdx.x; i < en; i += 256) {
        int r = rec[i];
        int s = r & 0xFFFF;
        int slot = atomicAdd(&cur[(r >> 16) & 63], 1);
        es[st + slot] = make_int2(s, __float_as_int(inv[s]));
    }
}

// ---------------- W pre-conversion: fp32 [K][cout] -> bf16 hi/lo, transposed
// [col][K] with 16B XOR swizzle pre-applied (ready for linear LDS staging).
__global__ void k_wcvt(const float* __restrict__ W, ush* __restrict__ wh,
                       ush* __restrict__ wl, int csh, int total) {
    int i = blockIdx.x * 256 + threadIdx.x;
    if (i >= total) return;
    int k = i >> csh;
    int col = i & ((1 << csh) - 1);
    float w = W[i];
    ush hi = f2bf(w);
    ush lo = f2bf(w - bfl((uint32)hi));
    int byte = ((col * 128 + k) * 2) ^ ((col & 7) << 4);
    *(ush*)((char*)wh + byte) = hi;
    *(ush*)((char*)wl + byte) = lo;
}

// ---------------- MFMA GEMM layer 1: fp32 x, bf16x3 split ----------------
// h[n,128](bf16) = x[n,128] @ W1. Block 128 rows, 4 waves 2x2, K=128 one-shot.
// W pre-converted (transposed+swizzled) -> linear short8 staging.
__global__ __launch_bounds__(256) void k_gemm1m(const float* __restrict__ x,
                                                const ush* __restrict__ gwh,
                                                const ush* __restrict__ gwl,
                                                ush* __restrict__ h, int n) {
    constexpr int COUT = 128, CT = 4;
    __shared__ short xh[128 * 128];        // 32 KiB
    __shared__ short xl[128 * 128];        // 32 KiB
    __shared__ short wh[COUT * 128];       // 32 KiB
    __shared__ short wl[COUT * 128];       // 32 KiB
    int tid = threadIdx.x;
    int row0 = blockIdx.x * 128;

    for (int i = tid; i < COUT * 16; i += 256) {   // COUT*128/8 short8 units
        ((short8*)wh)[i] = ((const short8*)gwh)[i];
        ((short8*)wl)[i] = ((const short8*)gwl)[i];
    }
    #pragma unroll
    for (int i = 0; i < 8; ++i) {
        int rl = (tid >> 4) + i * 16;
        int k0 = (tid & 15) * 8;
        int row = row0 + rl;
        float f[8];
        if (row < n) {
            float4 p0 = *(const float4*)&x[(size_t)row * 128 + k0];
            float4 p1 = *(const float4*)&x[(size_t)row * 128 + k0 + 4];
            f[0] = p0.x; f[1] = p0.y; f[2] = p0.z; f[3] = p0.w;
            f[4] = p1.x; f[5] = p1.y; f[6] = p1.z; f[7] = p1.w;
        } else {
            #pragma unroll
            for (int j = 0; j < 8; ++j) f[j] = 0.f;
        }
        short8 hi, lo;
        #pragma unroll
        for (int j = 0; j < 8; ++j) {
            ush hb = f2bf(f[j]);
            hi[j] = (short)hb;
            lo[j] = (short)f2bf(f[j] - bfl((uint32)hb));
        }
        int byte = (rl * 256 + k0 * 2) ^ ((rl & 7) << 4);
        *(short8*)((char*)xh + byte) = hi;
        *(short8*)((char*)xl + byte) = lo;
    }
    __syncthreads();

    int wid = tid >> 6, lane = tid & 63;
    int arow = (wid >> 1) * 64;
    int bcol = (wid & 1) * (COUT / 2);
    int l15 = lane & 15, kg = lane >> 4;

    f32x4 acc[4][CT];
    #pragma unroll
    for (int rt = 0; rt < 4; ++rt)
        #pragma unroll
        for (int ct = 0; ct < CT; ++ct)
            acc[rt][ct] = (f32x4){0.f, 0.f, 0.f, 0.f};

    #pragma unroll
    for (int ks = 0; ks < 4; ++ks) {
        short8 ah[4], al[4];
        #pragma unroll
        for (int rt = 0; rt < 4; ++rt) {
            int r = arow + rt * 16 + l15;
            int byte = (r * 256 + ks * 64 + kg * 16) ^ ((r & 7) << 4);
            ah[rt] = *(const short8*)((const char*)xh + byte);
            al[rt] = *(const short8*)((const char*)xl + byte);
        }
        #pragma unroll
        for (int ct = 0; ct < CT; ++ct) {
            int c = bcol + ct * 16 + l15;
            int byte = (c * 256 + ks * 64 + kg * 16) ^ ((c & 7) << 4);
            short8 bh = *(const short8*)((const char*)wh + byte);
            short8 bl = *(const short8*)((const char*)wl + byte);
            #pragma unroll
            for (int rt = 0; rt < 4; ++rt) {
                acc[rt][ct] = __builtin_amdgcn_mfma_f32_16x16x32_bf16(ah[rt], bh, acc[rt][ct], 0, 0, 0);
                acc[rt][ct] = __builtin_amdgcn_mfma_f32_16x16x32_bf16(al[rt], bh, acc[rt][ct], 0, 0, 0);
                acc[rt][ct] = __builtin_amdgcn_mfma_f32_16x16x32_bf16(ah[rt], bl, acc[rt][ct], 0, 0, 0);
            }
        }
    }

    int rq = kg * 4;
    #pragma unroll
    for (int rt = 0; rt < 4; ++rt)
        #pragma unroll
        for (int ct = 0; ct < CT; ++ct) {
            int col = bcol + ct * 16 + l15;
            #pragma unroll
            for (int q = 0; q < 4; ++q) {
                int row = row0 + arow + rt * 16 + rq + q;
                if (row < n) h[(size_t)row * COUT + col] = f2bf(acc[rt][ct][q]);
            }
        }
}

// ---------------- MFMA GEMM layer 2: bf16 act input, bf16x2 split ----------
// h[n,64](bf16) = a[n,128](bf16) @ W2. LDS 64KB -> 2 blocks/CU. Pre-conv W.
__global__ __launch_bounds__(256) void k_gemm2m(const ush* __restrict__ a,
                                                const ush* __restrict__ gwh,
                                                const ush* __restrict__ gwl,
                                                ush* __restrict__ h, int n) {
    constexpr int COUT = 64, CT = 2;
    __shared__ short xh[128 * 128];        // 32 KiB
    __shared__ short wh[COUT * 128];       // 16 KiB
    __shared__ short wl[COUT * 128];       // 16 KiB
    int tid = threadIdx.x;
    int row0 = blockIdx.x * 128;

    for (int i = tid; i < COUT * 16; i += 256) {
        ((short8*)wh)[i] = ((const short8*)gwh)[i];
        ((short8*)wl)[i] = ((const short8*)gwl)[i];
    }
    #pragma unroll
    for (int i = 0; i < 8; ++i) {
        int rl = (tid >> 4) + i * 16;
        int k0 = (tid & 15) * 8;
        int row = row0 + rl;
        short8 v;
        #pragma unroll
        for (int j = 0; j < 8; ++j) v[j] = 0;
        if (row < n) v = *(const short8*)&a[(size_t)row * 128 + k0];
        int byte = (rl * 256 + k0 * 2) ^ ((rl & 7) << 4);
        *(short8*)((char*)xh + byte) = v;
    }
    __syncthreads();

    int wid = tid >> 6, lane = tid & 63;
    int arow = (wid >> 1) * 64;
    int bcol = (wid & 1) * (COUT / 2);
    int l15 = lane & 15, kg = lane >> 4;

    f32x4 acc[4][CT];
    #pragma unroll
    for (int rt = 0; rt < 4; ++rt)
        #pragma unroll
        for (int ct = 0; ct < CT; ++ct)
            acc[rt][ct] = (f32x4){0.f, 0.f, 0.f, 0.f};

    #pragma unroll
    for (int ks = 0; ks < 4; ++ks) {
        short8 ah[4];
        #pragma unroll
        for (int rt = 0; rt < 4; ++rt) {
            int r = arow + rt * 16 + l15;
            int byte = (r * 256 + ks * 64 + kg * 16) ^ ((r & 7) << 4);
            ah[rt] = *(const short8*)((const char*)xh + byte);
        }
        #pragma unroll
        for (int ct = 0; ct < CT; ++ct) {
            int c = bcol + ct * 16 + l15;
            int byte = (c * 256 + ks * 64 + kg * 16) ^ ((c & 7) << 4);
            short8 bh = *(const short8*)((const char*)wh + byte);
            short8 bl = *(const short8*)((const char*)wl + byte);
            #pragma unroll
            for (int rt = 0; rt < 4; ++rt) {
                acc[rt][ct] = __builtin_amdgcn_mfma_f32_16x16x32_bf16(ah[rt], bh, acc[rt][ct], 0, 0, 0);
                acc[rt][ct] = __builtin_amdgcn_mfma_f32_16x16x32_bf16(ah[rt], bl, acc[rt][ct], 0, 0, 0);
            }
        }
    }

    int rq = kg * 4;
    #pragma unroll
    for (int rt = 0; rt < 4; ++rt)
        #pragma unroll
        for (int ct = 0; ct < CT; ++ct) {
            int col = bcol + ct * 16 + l15;
            #pragma unroll
            for (int q = 0; q < 4; ++q) {
                int row = row0 + arow + rt * 16 + rq + q;
                if (row < n) h[(size_t)row * COUT + col] = f2bf(acc[rt][ct][q]);
            }
        }
}

// ---------------- Gather (aggregation), bf16 source rows ----------------
// es[i] = {src, bits(inv_sqrt[src])}. One wave per destination node.
// OUTBF: write bf16 (layer-1 act); else fp32 (final out).
template <int COLS, bool RELU, bool OUTBF>
__global__ __launch_bounds__(256) void k_gather(const ush* __restrict__ h,
                                                const int* __restrict__ rowstart,
                                                const int2* __restrict__ es,
                                                const float* __restrict__ inv,
                                                const float* __restrict__ bias,
                                                void* __restrict__ outp, int n) {
    int wave = threadIdx.x >> 6;
    int lane = threadIdx.x & 63;
    int node = blockIdx.x * 4 + wave;
    if (node >= n) return;
    int s0 = rowstart[node];
    int s1 = rowstart[node + 1];
    float iv = inv[node];

    if constexpr (COLS == 128) {
        int c = lane * 2;
        float accx = 0.f, accy = 0.f;
        int i = s0;
        for (; i + 8 <= s1; i += 8) {
            int    a[8];
            float  w[8];
            uint32 u[8];
            #pragma unroll
            for (int j = 0; j < 8; ++j) {
                int2 r = es[i + j];
                a[j] = r.x;
                w[j] = __int_as_float(r.y);
            }
            #pragma unroll
            for (int j = 0; j < 8; ++j)
                u[j] = *(const uint32*)&h[(size_t)a[j] * 128 + c];
            #pragma unroll
            for (int j = 0; j < 8; ++j) {
                accx += w[j] * bfl(u[j]);
                accy += w[j] * bfh(u[j]);
            }
        }
        for (; i < s1; ++i) {
            int2 r = es[i];
            uint32 u = *(const uint32*)&h[(size_t)r.x * 128 + c];
            float w = __int_as_float(r.y);
            accx += w * bfl(u);
            accy += w * bfh(u);
        }
        uint32 us = *(const uint32*)&h[(size_t)node * 128 + c];
        float2 bb = *(const float2*)&bias[c];
        float ox = iv * accx + iv * iv * bfl(us) + bb.x;
        float oy = iv * accy + iv * iv * bfh(us) + bb.y;
        if (RELU) { ox = fmaxf(ox, 0.f); oy = fmaxf(oy, 0.f); }
        if constexpr (OUTBF) {
            uint32 pk = (uint32)f2bf(ox) | ((uint32)f2bf(oy) << 16);
            *(uint32*)&((ush*)outp)[(size_t)node * 128 + c] = pk;
        } else {
            *(float2*)&((float*)outp)[(size_t)node * 128 + c] = make_float2(ox, oy);
        }
    } else {
        int c = lane;
        float acc = 0.f;
        int i = s0;
        for (; i + 8 <= s1; i += 8) {
            int   a[8];
            float w[8];
            ush   u[8];
            #pragma unroll
            for (int j = 0; j < 8; ++j) {
                int2 r = es[i + j];
                a[j] = r.x;
                w[j] = __int_as_float(r.y);
            }
            #pragma unroll
            for (int j = 0; j < 8; ++j)
                u[j] = h[(size_t)a[j] * 64 + c];
            #pragma unroll
            for (int j = 0; j < 8; ++j)
                acc += w[j] * bfl((uint32)u[j]);
        }
        for (; i < s1; ++i) {
            int2 r = es[i];
            acc += __int_as_float(r.y) * bfl((uint32)h[(size_t)r.x * 64 + c]);
        }
        float self = bfl((uint32)h[(size_t)node * 64 + c]);
        float o = iv * acc + iv * iv * self + bias[c];
        if (RELU) o = fmaxf(o, 0.f);
        ((float*)outp)[(size_t)node * 64 + c] = o;
    }
}

// ---------------- launcher ----------------

extern "C" void kernel_launch(void* const* d_in, const int* in_sizes, int n_in,
                              void* d_out, int out_size, void* d_ws, size_t ws_size,
                              hipStream_t stream) {
    const float* x  = (const float*)d_in[0];
    const int*   ei = (const int*)d_in[1];
    const float* W1 = (const float*)d_in[2];
    const float* b1 = (const float*)d_in[3];
    const float* W2 = (const float*)d_in[4];
    const float* b2 = (const float*)d_in[5];
    float* out = (float*)d_out;

    const int N = in_sizes[0] / 128;   // 50000
    const int E = in_sizes[1] / 2;     // 800000
    const int NB = (N + 63) >> BSH;    // 782 buckets
    const int* src = ei;
    const int* dstp = ei + E;

    char* p = (char*)d_ws;
    auto take = [&](size_t bytes) {
        char* r = p;
        p += (bytes + 255) & ~(size_t)255;
        return r;
    };
    float* inv      = (float*)take((size_t)N * 4);
    int*   rowstart = (int*)take((size_t)(N + 1) * 4);
    int*   bcnt     = (int*)take((size_t)NB * 4);
    int*   bstart   = (int*)take((size_t)(NB + 1) * 4);
    int*   bcur     = (int*)take((size_t)NB * 4);
    int*   rec      = (int*)take((size_t)E * 4);         // packed src|dlocal
    int2*  es       = (int2*)take((size_t)E * 8);
    ush*   w1h      = (ush*)take(16384 * 2);
    ush*   w1l      = (ush*)take(16384 * 2);
    ush*   w2h      = (ush*)take(8192 * 2);
    ush*   w2l      = (ush*)take(8192 * 2);
    ush*   h1       = (ush*)take((size_t)N * 128 * 2);   // bf16
    ush*   act1     = (ush*)take((size_t)N * 128 * 2);   // bf16
    ush*   h2       = h1;   // h1 dead after gather-1

    const int nbC = (E + CHUNK - 1) / CHUNK;   // 196

    k_zerob <<<(NB + 255) / 256, 256, 0, stream>>>(bcnt, NB);
    k_bcount<<<nbC, 256, 0, stream>>>(dstp, bcnt, E, NB);
    k_bscan <<<1, 256, 0, stream>>>(bcnt, bstart, bcur, NB, E);
    k_binA2 <<<nbC, 256, 0, stream>>>(src, dstp, bcur, rec, E, NB);
    k_degB  <<<NB, 256, 0, stream>>>(rec, bstart, rowstart, inv, N, E);
    k_fillB2<<<NB, 256, 0, stream>>>(rec, bstart, rowstart, inv, es, N);

    k_wcvt<<<64, 256, 0, stream>>>(W1, w1h, w1l, 7, 16384);
    k_wcvt<<<32, 256, 0, stream>>>(W2, w2h, w2l, 6, 8192);

    const int gb = (N + 127) / 128;   // 391
    k_gemm1m<<<gb, 256, 0, stream>>>(x, w1h, w1l, h1, N);
    k_gather<128, true, true><<<(N + 3) / 4, 256, 0, stream>>>(h1, rowstart, es, inv, b1, act1, N);
    k_gemm2m<<<gb, 256, 0, stream>>>(act1, w2h, w2l, h2, N);
    k_gather<64, false, false><<<(N + 3) / 4, 256, 0, stream>>>(h2, rowstart, es, inv, b2, out, N);
}